// Round 5
// baseline (1382.432 us; speedup 1.0000x reference)
//
#include <hip/hip_runtime.h>
#include <math.h>

#define T_SEQ 2048
#define NHQ 32
#define NG 2
#define HD 64
#define CSTRIDE 16
#define SCALE 0.125f
#define KVGW 384  // fused k|v|gate row width: 128 k + 128 v + 3 gate + pad

typedef __attribute__((ext_vector_type(8))) short short8_t;
typedef __attribute__((ext_vector_type(4))) short short4_t;
typedef __attribute__((ext_vector_type(4))) float f32x4;

__device__ __forceinline__ ushort f2bf(float x) {  // round-to-nearest-even
  union { float f; unsigned u; } c; c.f = x;
  unsigned r = c.u + 0x7fff + ((c.u >> 16) & 1);
  return (ushort)(r >> 16);
}
__device__ __forceinline__ short pbf(float x) {  // cheap round-half-up (x>=0)
  union { float f; unsigned u; } c; c.f = x;
  return (short)((c.u + 0x8000u) >> 16);
}
__device__ __forceinline__ float bf2f(short u) {
  union { unsigned u; float f; } c; c.u = ((unsigned)(ushort)u) << 16;
  return c.f;
}

__device__ __forceinline__ void glds16(const ushort* g, ushort* l) {
  __builtin_amdgcn_global_load_lds(
      (const __attribute__((address_space(1))) unsigned int*)g,
      (__attribute__((address_space(3))) unsigned int*)l, 16, 0, 0);
}

// ---- bf16 MFMA GEMM: C[M,N] = A[M,K] * B[N,K]^T (m97 recipe + XOR swizzle)
__global__ __launch_bounds__(256) void mgemm(
    const ushort* __restrict__ A, const ushort* __restrict__ B,
    float* __restrict__ C, int M, int N, int K) {
  __shared__ __align__(16) ushort As[128 * 64];
  __shared__ __align__(16) ushort Bs[128 * 64];
  const int tid = threadIdx.x;
  const int lane = tid & 63, w = tid >> 6;
  const int quad = lane >> 4, l16 = lane & 15;
  const int m0 = blockIdx.y * 128, n0 = blockIdx.x * 128;
  const int mq = (w & 1) * 64, nq = (w >> 1) * 64;
  f32x4 acc[4][4];
  const f32x4 fz = {0.f, 0.f, 0.f, 0.f};
  #pragma unroll
  for (int i = 0; i < 4; ++i)
    #pragma unroll
    for (int j = 0; j < 4; ++j) acc[i][j] = fz;

  for (int k0 = 0; k0 < K; k0 += 64) {
    __syncthreads();
    #pragma unroll
    for (int j = 0; j < 4; ++j) {
      int ci = j * 256 + tid;
      int row = ci >> 3, cl = ci & 7;
      int kc = cl ^ (row & 7);
      glds16(A + ((size_t)(m0 + row) * K + k0 + kc * 8), &As[ci * 8]);
      glds16(B + ((size_t)(n0 + row) * K + k0 + kc * 8), &Bs[ci * 8]);
    }
    __syncthreads();
    #pragma unroll
    for (int kt = 0; kt < 2; ++kt) {
      short8_t af[4], bf_[4];
      #pragma unroll
      for (int mt = 0; mt < 4; ++mt) {
        int row = mq + mt * 16 + l16;
        int cl = (kt * 4 + quad) ^ (row & 7);
        af[mt] = *(const short8_t*)&As[row * 64 + cl * 8];
      }
      #pragma unroll
      for (int nt = 0; nt < 4; ++nt) {
        int row = nq + nt * 16 + l16;
        int cl = (kt * 4 + quad) ^ (row & 7);
        bf_[nt] = *(const short8_t*)&Bs[row * 64 + cl * 8];
      }
      #pragma unroll
      for (int mt = 0; mt < 4; ++mt)
        #pragma unroll
        for (int nt = 0; nt < 4; ++nt)
          acc[mt][nt] = __builtin_amdgcn_mfma_f32_16x16x32_bf16(
              af[mt], bf_[nt], acc[mt][nt], 0, 0, 0);
    }
  }
  #pragma unroll
  for (int mt = 0; mt < 4; ++mt)
    #pragma unroll
    for (int nt = 0; nt < 4; ++nt)
      #pragma unroll
      for (int r = 0; r < 4; ++r) {
        int m = m0 + mq + mt * 16 + quad * 4 + r;
        int n = n0 + nq + nt * 16 + l16;
        C[(size_t)m * N + n] = acc[mt][nt][r];
      }
}

// ---------------- conversions / packing ----------------
__global__ __launch_bounds__(256) void cvt_bf(const float* __restrict__ src,
                                              ushort* __restrict__ dst, int n) {
  int i = blockIdx.x * 256 + threadIdx.x;
  if (i < n) dst[i] = f2bf(src[i]);
}

__global__ __launch_bounds__(256) void cvt_sum2_bf(const float* __restrict__ a,
                                                   const float* __restrict__ b,
                                                   ushort* __restrict__ dst, int n) {
  int i = blockIdx.x * 256 + threadIdx.x;
  if (i < n) dst[i] = f2bf(a[i] + b[i]);
}

__global__ __launch_bounds__(256) void pack_wkvg(
    const float* __restrict__ Wk, const float* __restrict__ Wv,
    const float* __restrict__ Wg, ushort* __restrict__ dst) {
  int i = blockIdx.x * 256 + threadIdx.x;
  if (i >= KVGW * 2048) return;
  int n = i >> 11, k = i & 2047;
  float v;
  if (n < 128) v = Wk[(size_t)n * 2048 + k];
  else if (n < 256) v = Wv[(size_t)(n - 128) * 2048 + k];
  else if (n < 259) v = Wg[(size_t)(n - 256) * 2048 + k];
  else v = 0.f;
  dst[i] = f2bf(v);
}

// vt[g][d][s] bf16 from kvg v-part (v is NOT roped)
__global__ __launch_bounds__(256) void cvt_vt(const float* __restrict__ kvg,
                                              ushort* __restrict__ vt) {
  int i = blockIdx.x * 256 + threadIdx.x;
  if (i >= T_SEQ * NG * HD) return;
  int d = i & 63, g = (i >> 6) & 1, s = i >> 7;
  vt[((size_t)g * HD + d) * T_SEQ + s] =
      f2bf(kvg[(size_t)s * KVGW + 128 + g * 64 + d]);
}

// ------- RoPE: q fp32 -> qbf bf16 (fp32 q not written back);
//         kvg k-part roped in place (fp32, for compress) + kbf bf16 -------
__global__ __launch_bounds__(256) void rope_all(
    const float* __restrict__ q, float* __restrict__ kvg,
    ushort* __restrict__ qbf, ushort* __restrict__ kbf) {
  const int t = blockIdx.x;
  const float lnb_over = 9.210340371976184f / 32.f;  // ln(10000)/32
  for (int job = threadIdx.x; job < (NHQ + NG) * 32; job += 256) {
    int h = job >> 5, j = job & 31;
    float inv = expf(-(float)j * lnb_over);
    float fr = (float)t * inv;
    float c_ = cosf(fr), s_ = sinf(fr);
    if (h < NHQ) {
      const float* base = q + ((size_t)t * NHQ + h) * HD;
      float x1 = base[j], x2 = base[j + 32];
      ushort* ob = qbf + ((size_t)t * NHQ + h) * HD;
      ob[j] = f2bf(x1 * c_ - x2 * s_);
      ob[j + 32] = f2bf(x2 * c_ + x1 * s_);
    } else {
      int g = h - NHQ;
      float* base = kvg + (size_t)t * KVGW + g * 64;
      float x1 = base[j], x2 = base[j + 32];
      float o1 = x1 * c_ - x2 * s_, o2 = x2 * c_ + x1 * s_;
      base[j] = o1; base[j + 32] = o2;
      kbf[(size_t)t * 128 + g * 64 + j] = f2bf(o1);
      kbf[(size_t)t * 128 + g * 64 + j + 32] = f2bf(o2);
    }
  }
}

// ---------------- compression -> ck16[c][g][d], cvT16[g][d][c] bf16 --------
__global__ __launch_bounds__(256) void compress_kv(
    const float* __restrict__ kvg,
    const float* __restrict__ Wck, const float* __restrict__ Wcv,
    ushort* __restrict__ ck16, ushort* __restrict__ cvT16) {
  const int c = blockIdx.x, g = blockIdx.y;
  const int tid = threadIdx.x;
  const int d = tid & 63, chunk = tid >> 6;
  __shared__ float red[2][4][64];
  float ak = 0.f, av = 0.f;
  for (int f = chunk * 512; f < chunk * 512 + 512; ++f) {
    int i = f >> 6, e = f & 63;
    int trow = c * CSTRIDE + i;
    float kv = kvg[(size_t)trow * KVGW + g * 64 + e];
    float vv = kvg[(size_t)trow * KVGW + 128 + g * 64 + e];
    ak += kv * Wck[((size_t)g * 2048 + f) * HD + d];
    av += vv * Wcv[((size_t)g * 2048 + f) * HD + d];
  }
  red[0][chunk][d] = ak;
  red[1][chunk][d] = av;
  __syncthreads();
  if (tid < 64) {
    ck16[((size_t)c * 2 + g) * 64 + tid] =
        f2bf(red[0][0][tid] + red[0][1][tid] + red[0][2][tid] + red[0][3][tid]);
  } else if (tid < 128) {
    int dd = tid - 64;
    cvT16[((size_t)g * 64 + dd) * 128 + c] =
        f2bf(red[1][0][dd] + red[1][1][dd] + red[1][2][dd] + red[1][3][dd]);
  }
}

// ------- MFMA compressed attention + block scores + top-16 selection -------
// wg = (qb: 64 queries, g). 4 waves x 4 heads. S^T = CK Q^T; O^T = CV^T P^T.
__global__ __launch_bounds__(256, 1) void comp_attn2(
    const ushort* __restrict__ qbf, const ushort* __restrict__ ck16,
    const ushort* __restrict__ cvT16, const float* __restrict__ kvg,
    float* __restrict__ comb1, unsigned* __restrict__ sel_out) {
  const int qb = blockIdx.x, g = blockIdx.y;
  const int tid = threadIdx.x, lane = tid & 63, w = tid >> 6;
  const int quad = lane >> 4, l16 = lane & 15;
  const int t0 = qb * 64;
  const int ctn = min(8, (4 * qb + 18) >> 4);  // ceil(nv_tile/16)

  __shared__ float psum[64][129];  // sum over heads of p/l, 33 KB
  __shared__ float scs_dummy;      // (none)

  for (int i = tid; i < 64 * 129; i += 256) ((float*)psum)[i] = 0.f;

  // CK A-frags (shared by all heads): A[m=c][k=d]
  short8_t ckA[8][2];
  #pragma unroll
  for (int ct = 0; ct < 8; ++ct) {
    if (ct >= ctn) continue;
    #pragma unroll
    for (int kt = 0; kt < 2; ++kt)
      ckA[ct][kt] = *(const short8_t*)(ck16 +
          ((size_t)(ct * 16 + l16) * 2 + g) * 64 + kt * 32 + quad * 8);
  }
  // CV^T A-frags: A[m=d][k=c]
  short4_t cvA[8][4];
  #pragma unroll
  for (int ct = 0; ct < 8; ++ct) {
    if (ct >= ctn) continue;
    #pragma unroll
    for (int dt = 0; dt < 4; ++dt)
      cvA[ct][dt] = *(const short4_t*)(cvT16 +
          ((size_t)g * 64 + dt * 16 + l16) * 128 + ct * 16 + quad * 4);
  }
  int cmax[4]; float gate[4];
  #pragma unroll
  for (int qt = 0; qt < 4; ++qt) {
    int t = t0 + qt * 16 + l16;
    cmax[qt] = (t - 31) >> 4;  // negative -> all masked
    gate[qt] = 1.f / (1.f + __expf(-kvg[(size_t)t * KVGW + 256]));
  }
  __syncthreads();  // psum zeroed

  const f32x4 fz = {0.f, 0.f, 0.f, 0.f};
  for (int hi = 0; hi < 4; ++hi) {
    const int head = g * 16 + w * 4 + hi;
    short8_t qB[4][2];
    #pragma unroll
    for (int qt = 0; qt < 4; ++qt)
      #pragma unroll
      for (int kt = 0; kt < 2; ++kt)
        qB[qt][kt] = *(const short8_t*)(qbf +
            ((size_t)(t0 + qt * 16 + l16) * NHQ + head) * HD + kt * 32 + quad * 8);

    #pragma unroll
    for (int qt = 0; qt < 4; ++qt) {
      f32x4 sp[8];
      #pragma unroll
      for (int ct = 0; ct < 8; ++ct) {
        if (ct >= ctn) continue;
        f32x4 c0 = __builtin_amdgcn_mfma_f32_16x16x32_bf16(ckA[ct][0], qB[qt][0], fz, 0, 0, 0);
        sp[ct] = __builtin_amdgcn_mfma_f32_16x16x32_bf16(ckA[ct][1], qB[qt][1], c0, 0, 0, 0);
      }
      // mask + softmax (single pass; reduce across quads = same query)
      float mx = -1e30f;
      #pragma unroll
      for (int ct = 0; ct < 8; ++ct) {
        if (ct >= ctn) continue;
        #pragma unroll
        for (int r = 0; r < 4; ++r) {
          int c = ct * 16 + quad * 4 + r;
          float s_ = (c <= cmax[qt]) ? sp[ct][r] * SCALE : -1e30f;
          sp[ct][r] = s_;
          mx = fmaxf(mx, s_);
        }
      }
      mx = fmaxf(mx, __shfl_xor(mx, 16));
      mx = fmaxf(mx, __shfl_xor(mx, 32));
      float pf[8][4];
      short4_t pB[8];
      float sum = 0.f;
      #pragma unroll
      for (int ct = 0; ct < 8; ++ct) {
        if (ct >= ctn) continue;
        short4_t pb;
        #pragma unroll
        for (int r = 0; r < 4; ++r) {
          float p = __expf(sp[ct][r] - mx);
          pf[ct][r] = p; sum += p;
          pb[r] = pbf(p);
        }
        pB[ct] = pb;
      }
      sum += __shfl_xor(sum, 16);
      sum += __shfl_xor(sum, 32);
      const float inv = (cmax[qt] >= 0) ? 1.f / sum : 0.f;  // zero invalid rows
      const int q_l = qt * 16 + l16;
      #pragma unroll
      for (int ct = 0; ct < 8; ++ct) {
        if (ct >= ctn) continue;
        #pragma unroll
        for (int r = 0; r < 4; ++r)
          atomicAdd(&psum[q_l][ct * 16 + quad * 4 + r], pf[ct][r] * inv);
      }
      // O^T = CV^T P^T
      f32x4 oc[4];
      #pragma unroll
      for (int dt = 0; dt < 4; ++dt) oc[dt] = fz;
      #pragma unroll
      for (int ct = 0; ct < 8; ++ct) {
        if (ct >= ctn) continue;
        #pragma unroll
        for (int dt = 0; dt < 4; ++dt)
          oc[dt] = __builtin_amdgcn_mfma_f32_16x16x16bf16_1k(
              cvA[ct][dt], pB[ct], oc[dt], 0, 0, 0);
      }
      const float sc = gate[qt] * inv;
      const int t = t0 + q_l;
      #pragma unroll
      for (int dt = 0; dt < 4; ++dt) {
        f32x4 o = oc[dt];
        #pragma unroll
        for (int r = 0; r < 4; ++r) o[r] *= sc;
        *(f32x4*)(comb1 + ((size_t)t * NHQ + head) * HD + dt * 16 + quad * 4) = o;
      }
    }
  }
  __syncthreads();  // psum complete

  // block scores + top-16, one thread per query
  if (tid < 64) {
    const int t = t0 + tid;
    float s[32];
    #pragma unroll
    for (int b = 0; b < 32; ++b) {
      float v;
      if (b > qb) v = -INFINITY;
      else if (b == 0 || qb - b < 2) v = INFINITY;
      else v = psum[tid][4 * b - 1] + psum[tid][4 * b] + psum[tid][4 * b + 1] +
               psum[tid][4 * b + 2] + psum[tid][4 * b + 3];
      s[b] = v;
    }
    unsigned m_ = 0, picked = 0;
    #pragma unroll 1
    for (int it = 0; it < 16; ++it) {
      float best = -INFINITY; int bi = -1;
      #pragma unroll
      for (int b = 0; b < 32; ++b)
        if (!((picked >> b) & 1u) && s[b] > best) { best = s[b]; bi = b; }
      if (bi < 0) break;
      m_ |= 1u << bi;
      picked |= 1u << bi;
    }
    sel_out[(size_t)t * NG + g] = m_;
  }
}

// ------- MFMA flash attention, transposed, split-K flash-decode:
// 8 waves: waves {w, w+4} same head, even/odd halves of block list; LDS merge.
__global__ __launch_bounds__(512, 4) void mfma_attn(
    const ushort* __restrict__ qb16, const ushort* __restrict__ kb16,
    const ushort* __restrict__ vtb, const float* __restrict__ kvg,
    const unsigned* __restrict__ sel, float* __restrict__ comb1,
    float* __restrict__ comb2) {
  const int qb = blockIdx.x, g = blockIdx.y;
  const int hg = blockIdx.z & 3, mode = blockIdx.z >> 2;
  const int tid = threadIdx.x, lane = tid & 63, w = tid >> 6;
  const int quad = lane >> 4, l16 = lane & 15;
  const int head = g * 16 + hg * 4 + (w & 3);
  const int split = w >> 2;
  const int t0 = qb * 64;

  __shared__ unsigned sel_s[64];
  __shared__ float pml[4][2][4][64];      // [w-4][m|l][qt][lane]  8 KB
  __shared__ short4_t pacc[4][4][4][64];  // [w-4][dt][qt][lane] bf16 32 KB

  if (tid < 64) sel_s[tid] = sel[(size_t)(t0 + tid) * NG + g];
  __syncthreads();

  short8_t qB[4][2];
  #pragma unroll
  for (int qt = 0; qt < 4; ++qt)
    #pragma unroll
    for (int kd = 0; kd < 2; ++kd)
      qB[qt][kd] = *(const short8_t*)(qb16 +
          ((size_t)(t0 + qt * 16 + l16) * NHQ + head) * HD + kd * 32 + quad * 8);

  unsigned sbq[4];
  #pragma unroll
  for (int qt = 0; qt < 4; ++qt) sbq[qt] = sel_s[qt * 16 + l16];

  float m_[4], l_[4];
  f32x4 acc[4][4];
  const f32x4 fz = {0.f, 0.f, 0.f, 0.f};
  #pragma unroll
  for (int qt = 0; qt < 4; ++qt) { m_[qt] = -1e30f; l_[qt] = 0.f; }
  #pragma unroll
  for (int dt = 0; dt < 4; ++dt)
    #pragma unroll
    for (int qt = 0; qt < 4; ++qt) acc[dt][qt] = fz;

  // my half of the block list (interleaved for balance)
  unsigned mrem = 0; int b0 = 0, nb = 0;
  if (mode == 0) {
    unsigned uni = 0;
    for (int i = 0; i < 64; ++i) uni |= sel_s[i];
    int cnt = 0;
    while (uni) {
      int b = __ffs(uni) - 1; uni &= uni - 1;
      if ((cnt++ & 1) == split) mrem |= 1u << b;
    }
    nb = __popc(mrem);
  } else {
    b0 = ((qb > 8) ? qb - 8 : 0) + split;
    nb = (qb >= b0) ? (qb - b0) / 2 + 1 : 0;
  }

  for (int ib = 0; ib < nb; ++ib) {
    int blk;
    if (mode == 0) { blk = __ffs(mrem) - 1; mrem &= mrem - 1; } else { blk = b0 + 2 * ib; }

    // S^T = K Q^T
    f32x4 sp[4][4];
    #pragma unroll
    for (int kt = 0; kt < 4; ++kt) {
      const ushort* kr = kb16 + (size_t)(blk * 64 + kt * 16 + l16) * 128 + g * 64 + quad * 8;
      short8_t kA0 = *(const short8_t*)kr;
      short8_t kA1 = *(const short8_t*)(kr + 32);
      #pragma unroll
      for (int qt = 0; qt < 4; ++qt) {
        f32x4 c = __builtin_amdgcn_mfma_f32_16x16x32_bf16(kA0, qB[qt][0], fz, 0, 0, 0);
        sp[kt][qt] = __builtin_amdgcn_mfma_f32_16x16x32_bf16(kA1, qB[qt][1], c, 0, 0, 0);
      }
    }

    // mask (-inf) + online softmax; m_ floor -1e30 makes any block order safe
    short4_t pB[4][4];
    #pragma unroll
    for (int qt = 0; qt < 4; ++qt) {
      const int qg = t0 + qt * 16 + l16;
      float mx = -INFINITY;
      #pragma unroll
      for (int kt = 0; kt < 4; ++kt)
        #pragma unroll
        for (int r = 0; r < 4; ++r) {
          int key = blk * 64 + kt * 16 + quad * 4 + r;
          bool ok = (key <= qg) &&
                    (mode == 0 ? (((sbq[qt] >> blk) & 1u) != 0) : (qg - key <= 512));
          float s_ = ok ? sp[kt][qt][r] * SCALE : -INFINITY;
          sp[kt][qt][r] = s_;
          mx = fmaxf(mx, s_);
        }
      mx = fmaxf(mx, __shfl_xor(mx, 16));
      mx = fmaxf(mx, __shfl_xor(mx, 32));
      float mnew = fmaxf(m_[qt], mx);  // >= -1e30 always
      float alpha = __expf(m_[qt] - mnew);
      m_[qt] = mnew;
      float ps = 0.f;
      #pragma unroll
      for (int kt = 0; kt < 4; ++kt) {
        short4_t pb;
        #pragma unroll
        for (int r = 0; r < 4; ++r) {
          float p = __expf(sp[kt][qt][r] - mnew);  // exp(-inf)=0
          ps += p;
          pb[r] = pbf(p);
        }
        pB[kt][qt] = pb;
      }
      ps += __shfl_xor(ps, 16);
      ps += __shfl_xor(ps, 32);
      l_[qt] = l_[qt] * alpha + ps;
      #pragma unroll
      for (int dt = 0; dt < 4; ++dt)
        #pragma unroll
        for (int r = 0; r < 4; ++r) acc[dt][qt][r] *= alpha;
    }

    // O^T += V^T P^T
    #pragma unroll
    for (int kt = 0; kt < 4; ++kt) {
      short4_t vA[4];
      #pragma unroll
      for (int dt = 0; dt < 4; ++dt)
        vA[dt] = *(const short4_t*)(vtb +
            ((size_t)g * HD + dt * 16 + l16) * T_SEQ + blk * 64 + kt * 16 + quad * 4);
      #pragma unroll
      for (int dt = 0; dt < 4; ++dt)
        #pragma unroll
        for (int qt = 0; qt < 4; ++qt)
          acc[dt][qt] = __builtin_amdgcn_mfma_f32_16x16x16bf16_1k(
              vA[dt], pB[kt][qt], acc[dt][qt], 0, 0, 0);
    }
  }

  // publish split-1 partials, merge in split-0 waves
  if (split == 1) {
    const int w4 = w & 3;
    #pragma unroll
    for (int qt = 0; qt < 4; ++qt) {
      pml[w4][0][qt][lane] = m_[qt];
      pml[w4][1][qt][lane] = l_[qt];
    }
    #pragma unroll
    for (int dt = 0; dt < 4; ++dt)
      #pragma unroll
      for (int qt = 0; qt < 4; ++qt) {
        short4_t pk;
        #pragma unroll
        for (int r = 0; r < 4; ++r) pk[r] = pbf(fmaxf(acc[dt][qt][r], 0.f)) , pk[r] = (short)f2bf(acc[dt][qt][r]);
        pacc[w4][dt][qt][lane] = pk;
      }
  }
  __syncthreads();
  if (split == 0) {
    float a1[4], a2[4];
    #pragma unroll
    for (int qt = 0; qt < 4; ++qt) {
      float m2 = pml[w][0][qt][lane], l2 = pml[w][1][qt][lane];
      float mN = fmaxf(m_[qt], m2);
      a1[qt] = __expf(m_[qt] - mN);
      a2[qt] = __expf(m2 - mN);
      l_[qt] = l_[qt] * a1[qt] + l2 * a2[qt];
    }
    #pragma unroll
    for (int dt = 0; dt < 4; ++dt)
      #pragma unroll
      for (int qt = 0; qt < 4; ++qt) {
        short4_t pk = pacc[w][dt][qt][lane];
        #pragma unroll
        for (int r = 0; r < 4; ++r)
          acc[dt][qt][r] = acc[dt][qt][r] * a1[qt] + bf2f(pk[r]) * a2[qt];
      }
    // epilogue
    #pragma unroll
    for (int qt = 0; qt < 4; ++qt) {
      const int t = t0 + qt * 16 + l16;
      const float c_ =
          (1.f / (1.f + __expf(-kvg[(size_t)t * KVGW + 257 + mode]))) / l_[qt];
      #pragma unroll
      for (int dt = 0; dt < 4; ++dt)
        #pragma unroll
        for (int r = 0; r < 4; ++r) {
          const int d = dt * 16 + quad * 4 + r;
          size_t idx = ((size_t)t * NHQ + head) * HD + d;
          if (mode == 0) comb1[idx] += c_ * acc[dt][qt][r];
          else           comb2[idx]  = c_ * acc[dt][qt][r];
        }
    }
  }
}

extern "C" void kernel_launch(void* const* d_in, const int* in_sizes, int n_in,
                              void* d_out, int out_size, void* d_ws, size_t ws_size,
                              hipStream_t stream) {
  const float* x   = (const float*)d_in[0];
  const float* Wq  = (const float*)d_in[1];
  const float* Wk  = (const float*)d_in[2];
  const float* Wv  = (const float*)d_in[3];
  const float* Wo  = (const float*)d_in[4];
  const float* Wg  = (const float*)d_in[5];
  const float* Wck = (const float*)d_in[6];
  const float* Wcv = (const float*)d_in[7];
  float* out = (float*)d_out;
  float* ws = (float*)d_ws;

  float* qbuf   = ws;                           // 4,194,304 f
  float* comb1  = qbuf + 4194304;               // 4,194,304 f
  float* kvg    = comb1 + 4194304;              //   786,432 f
  ushort* ck16  = (ushort*)(kvg + 786432);      //    16,384 u16
  ushort* cvT16 = ck16 + 16384;                 //    16,384 u16
  unsigned* sel = (unsigned*)(cvT16 + 16384);   //     4,096 u32
  ushort* kbf   = (ushort*)(sel + 4096);        //   262,144 u16
  ushort* vtb   = kbf + 262144;                 //   262,144 u16
  ushort* wkvgb = vtb + 262144;                 //   786,432 u16
  ushort* regA  = wkvgb + 786432;               // 4,194,304 u16: xb -> combb
  ushort* regB  = regA + 4194304;               // 4,194,304 u16: wqb -> qbf
  ushort* xb = regA;      ushort* combb = regA;
  ushort* wqb = regB;     ushort* qbf = regB;
  float* comb2 = qbuf;                // fp32 q dead after rope_all
  ushort* wob = (ushort*)qbuf;        // written after comb2 consumed

  const int CV = (4194304 + 255) / 256;
  cvt_bf<<<CV, 256, 0, stream>>>(x, xb, 4194304);
  cvt_bf<<<CV, 256, 0, stream>>>(Wq, wqb, 4194304);
  pack_wkvg<<<(KVGW * 2048 + 255) / 256, 256, 0, stream>>>(Wk, Wv, Wg, wkvgb);

  mgemm<<<dim3(16, 16), 256, 0, stream>>>(xb, wqb, qbuf, 2048, 2048, 2048);
  mgemm<<<dim3(3, 16), 256, 0, stream>>>(xb, wkvgb, kvg, 2048, KVGW, 2048);

  rope_all<<<2048, 256, 0, stream>>>(qbuf, kvg, qbf, kbf);
  cvt_vt<<<(262144 + 255) / 256, 256, 0, stream>>>(kvg, vtb);
  compress_kv<<<dim3(127, 2), 256, 0, stream>>>(kvg, Wck, Wcv, ck16, cvT16);
  comp_attn2<<<dim3(32, 2), 256, 0, stream>>>(qbf, ck16, cvT16, kvg, comb1, sel);
  mfma_attn<<<dim3(32, 2, 8), 512, 0, stream>>>(qbf, kbf, vtb, kvg, sel, comb1, comb2);

  cvt_sum2_bf<<<CV, 256, 0, stream>>>(comb1, comb2, combb, 4194304);
  cvt_bf<<<CV, 256, 0, stream>>>(Wo, wob, 4194304);
  mgemm<<<dim3(16, 16), 256, 0, stream>>>(combb, wob, out, 2048, 2048, 2048);
}

// Round 6
// 682.109 us; speedup vs baseline: 2.0267x; 2.0267x over previous
//
#include <hip/hip_runtime.h>
#include <math.h>

#define T_SEQ 2048
#define NHQ 32
#define NG 2
#define HD 64
#define CSTRIDE 16
#define SCALE 0.125f
#define KVGW 384  // fused k|v|gate row width: 128 k + 128 v + 3 gate + pad

typedef __attribute__((ext_vector_type(8))) short short8_t;
typedef __attribute__((ext_vector_type(4))) short short4_t;
typedef __attribute__((ext_vector_type(4))) float f32x4;

__device__ __forceinline__ ushort f2bf(float x) {  // round-to-nearest-even
  union { float f; unsigned u; } c; c.f = x;
  unsigned r = c.u + 0x7fff + ((c.u >> 16) & 1);
  return (ushort)(r >> 16);
}
__device__ __forceinline__ short pbf(float x) {  // cheap round-half-up (x>=0)
  union { float f; unsigned u; } c; c.f = x;
  return (short)((c.u + 0x8000u) >> 16);
}
__device__ __forceinline__ float bf2f(ushort u) {
  union { unsigned u; float f; } c; c.u = ((unsigned)u) << 16;
  return c.f;
}

__device__ __forceinline__ void glds16(const ushort* g, ushort* l) {
  __builtin_amdgcn_global_load_lds(
      (const __attribute__((address_space(1))) unsigned int*)g,
      (__attribute__((address_space(3))) unsigned int*)l, 16, 0, 0);
}

// ---- bf16 MFMA GEMM: C[M,N] = A[M,K] * B[N,K]^T (m97 recipe + XOR swizzle)
__global__ __launch_bounds__(256) void mgemm(
    const ushort* __restrict__ A, const ushort* __restrict__ B,
    float* __restrict__ C, int M, int N, int K) {
  __shared__ __align__(16) ushort As[128 * 64];
  __shared__ __align__(16) ushort Bs[128 * 64];
  const int tid = threadIdx.x;
  const int lane = tid & 63, w = tid >> 6;
  const int quad = lane >> 4, l16 = lane & 15;
  const int m0 = blockIdx.y * 128, n0 = blockIdx.x * 128;
  const int mq = (w & 1) * 64, nq = (w >> 1) * 64;
  f32x4 acc[4][4];
  const f32x4 fz = {0.f, 0.f, 0.f, 0.f};
  #pragma unroll
  for (int i = 0; i < 4; ++i)
    #pragma unroll
    for (int j = 0; j < 4; ++j) acc[i][j] = fz;

  for (int k0 = 0; k0 < K; k0 += 64) {
    __syncthreads();
    #pragma unroll
    for (int j = 0; j < 4; ++j) {
      int ci = j * 256 + tid;
      int row = ci >> 3, cl = ci & 7;
      int kc = cl ^ (row & 7);
      glds16(A + ((size_t)(m0 + row) * K + k0 + kc * 8), &As[ci * 8]);
      glds16(B + ((size_t)(n0 + row) * K + k0 + kc * 8), &Bs[ci * 8]);
    }
    __syncthreads();
    #pragma unroll
    for (int kt = 0; kt < 2; ++kt) {
      short8_t af[4], bf_[4];
      #pragma unroll
      for (int mt = 0; mt < 4; ++mt) {
        int row = mq + mt * 16 + l16;
        int cl = (kt * 4 + quad) ^ (row & 7);
        af[mt] = *(const short8_t*)&As[row * 64 + cl * 8];
      }
      #pragma unroll
      for (int nt = 0; nt < 4; ++nt) {
        int row = nq + nt * 16 + l16;
        int cl = (kt * 4 + quad) ^ (row & 7);
        bf_[nt] = *(const short8_t*)&Bs[row * 64 + cl * 8];
      }
      #pragma unroll
      for (int mt = 0; mt < 4; ++mt)
        #pragma unroll
        for (int nt = 0; nt < 4; ++nt)
          acc[mt][nt] = __builtin_amdgcn_mfma_f32_16x16x32_bf16(
              af[mt], bf_[nt], acc[mt][nt], 0, 0, 0);
    }
  }
  #pragma unroll
  for (int mt = 0; mt < 4; ++mt)
    #pragma unroll
    for (int nt = 0; nt < 4; ++nt)
      #pragma unroll
      for (int r = 0; r < 4; ++r) {
        int m = m0 + mq + mt * 16 + quad * 4 + r;
        int n = n0 + nq + nt * 16 + l16;
        C[(size_t)m * N + n] = acc[mt][nt][r];
      }
}

// ---------------- conversions / packing ----------------
__global__ __launch_bounds__(256) void cvt_bf(const float* __restrict__ src,
                                              ushort* __restrict__ dst, int n) {
  int i = blockIdx.x * 256 + threadIdx.x;
  if (i < n) dst[i] = f2bf(src[i]);
}

__global__ __launch_bounds__(256) void cvt_sum2_bf(const float* __restrict__ a,
                                                   const float* __restrict__ b,
                                                   ushort* __restrict__ dst, int n) {
  int i = blockIdx.x * 256 + threadIdx.x;
  if (i < n) dst[i] = f2bf(a[i] + b[i]);
}

__global__ __launch_bounds__(256) void pack_wkvg(
    const float* __restrict__ Wk, const float* __restrict__ Wv,
    const float* __restrict__ Wg, ushort* __restrict__ dst) {
  int i = blockIdx.x * 256 + threadIdx.x;
  if (i >= KVGW * 2048) return;
  int n = i >> 11, k = i & 2047;
  float v;
  if (n < 128) v = Wk[(size_t)n * 2048 + k];
  else if (n < 256) v = Wv[(size_t)(n - 128) * 2048 + k];
  else if (n < 259) v = Wg[(size_t)(n - 256) * 2048 + k];
  else v = 0.f;
  dst[i] = f2bf(v);
}

// vt[g][d][s] bf16 from kvg v-part (v is NOT roped)
__global__ __launch_bounds__(256) void cvt_vt(const float* __restrict__ kvg,
                                              ushort* __restrict__ vt) {
  int i = blockIdx.x * 256 + threadIdx.x;
  if (i >= T_SEQ * NG * HD) return;
  int d = i & 63, g = (i >> 6) & 1, s = i >> 7;
  vt[((size_t)g * HD + d) * T_SEQ + s] =
      f2bf(kvg[(size_t)s * KVGW + 128 + g * 64 + d]);
}

// ------- RoPE: q fp32 -> qbf bf16; kvg k-part roped in place + kbf bf16 ----
__global__ __launch_bounds__(256) void rope_all(
    const float* __restrict__ q, float* __restrict__ kvg,
    ushort* __restrict__ qbf, ushort* __restrict__ kbf) {
  const int t = blockIdx.x;
  const float lnb_over = 9.210340371976184f / 32.f;  // ln(10000)/32
  for (int job = threadIdx.x; job < (NHQ + NG) * 32; job += 256) {
    int h = job >> 5, j = job & 31;
    float inv = expf(-(float)j * lnb_over);
    float fr = (float)t * inv;
    float c_ = cosf(fr), s_ = sinf(fr);
    if (h < NHQ) {
      const float* base = q + ((size_t)t * NHQ + h) * HD;
      float x1 = base[j], x2 = base[j + 32];
      ushort* ob = qbf + ((size_t)t * NHQ + h) * HD;
      ob[j] = f2bf(x1 * c_ - x2 * s_);
      ob[j + 32] = f2bf(x2 * c_ + x1 * s_);
    } else {
      int g = h - NHQ;
      float* base = kvg + (size_t)t * KVGW + g * 64;
      float x1 = base[j], x2 = base[j + 32];
      float o1 = x1 * c_ - x2 * s_, o2 = x2 * c_ + x1 * s_;
      base[j] = o1; base[j + 32] = o2;
      kbf[(size_t)t * 128 + g * 64 + j] = f2bf(o1);
      kbf[(size_t)t * 128 + g * 64 + j + 32] = f2bf(o2);
    }
  }
}

// ---------------- compression: fp32 ck/cv[c][g][d] ----------------
__global__ __launch_bounds__(256) void compress_kv(
    const float* __restrict__ kvg,
    const float* __restrict__ Wck, const float* __restrict__ Wcv,
    float* __restrict__ ck, float* __restrict__ cv) {
  const int c = blockIdx.x, g = blockIdx.y;
  const int tid = threadIdx.x;
  const int d = tid & 63, chunk = tid >> 6;
  __shared__ float red[2][4][64];
  float ak = 0.f, av = 0.f;
  for (int f = chunk * 512; f < chunk * 512 + 512; ++f) {
    int i = f >> 6, e = f & 63;
    int trow = c * CSTRIDE + i;
    float kv = kvg[(size_t)trow * KVGW + g * 64 + e];
    float vv = kvg[(size_t)trow * KVGW + 128 + g * 64 + e];
    ak += kv * Wck[((size_t)g * 2048 + f) * HD + d];
    av += vv * Wcv[((size_t)g * 2048 + f) * HD + d];
  }
  red[0][chunk][d] = ak;
  red[1][chunk][d] = av;
  __syncthreads();
  if (tid < 64) {
    ck[((size_t)c * NG + g) * HD + tid] =
        red[0][0][tid] + red[0][1][tid] + red[0][2][tid] + red[0][3][tid];
  } else if (tid < 128) {
    int dd = tid - 64;
    cv[((size_t)c * NG + g) * HD + dd] =
        red[1][0][dd] + red[1][1][dd] + red[1][2][dd] + red[1][3][dd];
  }
}

// ------- compressed attention + block scores + top-16 (scalar, bf16 q) -----
__global__ __launch_bounds__(128) void comp_attn(
    const ushort* __restrict__ qbf, const float* __restrict__ ck,
    const float* __restrict__ cv, const float* __restrict__ kvg,
    float* __restrict__ comb, unsigned* __restrict__ sel) {
  const int t = blockIdx.x, g = blockIdx.y;
  const int tid = threadIdx.x;
  __shared__ float qs[16][64];
  __shared__ float p[16][128];
  __shared__ float sc[32];
  for (int i = tid; i < 1024; i += 128)
    qs[i >> 6][i & 63] =
        bf2f(qbf[((size_t)t * NHQ + g * 16 + (i >> 6)) * HD + (i & 63)]);
  __syncthreads();
  const int cmaxv = (t >= 31) ? min(126, (t - 31) >> 4) : -1;
  const int nv = cmaxv + 1;
  for (int h = 0; h < 16; ++h) {
    for (int c = tid; c < nv; c += 128) {
      const float* ckp = ck + ((size_t)c * NG + g) * HD;
      float acc = 0.f;
      #pragma unroll
      for (int e = 0; e < 64; ++e) acc += qs[h][e] * ckp[e];
      p[h][c] = acc * SCALE;
    }
  }
  __syncthreads();
  if (tid < 16) {
    const int h = tid;
    float mx = -INFINITY;
    for (int c = 0; c < nv; ++c) mx = fmaxf(mx, p[h][c]);
    float s = 0.f;
    for (int c = 0; c < nv; ++c) { float e_ = expf(p[h][c] - mx); p[h][c] = e_; s += e_; }
    float is = (nv > 0) ? 1.f / s : 0.f;
    for (int c = 0; c < nv; ++c) p[h][c] *= is;
  }
  __syncthreads();
  const float g0 = 1.f / (1.f + expf(-kvg[(size_t)t * KVGW + 256]));
  for (int job = tid; job < 1024; job += 128) {
    int h = job >> 6, d = job & 63;
    float acc = 0.f;
    for (int c = 0; c < nv; ++c) acc += p[h][c] * cv[((size_t)c * NG + g) * HD + d];
    comb[((size_t)t * NHQ + g * 16 + h) * HD + d] = g0 * acc;
  }
  if (tid < 32) {
    const int b = tid, qb = t >> 6;
    float s;
    if (b > qb) s = -INFINITY;
    else if (b == 0 || qb - b < 2) s = INFINITY;
    else {
      s = 0.f;
      int clo = (4 * b - 1 > 0) ? 4 * b - 1 : 0;
      int chi = min(cmaxv, 4 * b + 3);
      for (int c = clo; c <= chi; ++c) {
        float cs_ = 0.f;
        for (int h = 0; h < 16; ++h) cs_ += p[h][c];
        s += cs_;
      }
    }
    sc[b] = s;
  }
  __syncthreads();
  if (tid == 0) {  // top-16, ties -> lowest index (matches jax.lax.top_k)
    unsigned m_ = 0;
    #pragma unroll 1
    for (int it = 0; it < 16; ++it) {
      float best = -INFINITY; int bi = -1;
      for (int b = 0; b < 32; ++b)
        if (sc[b] > best) { best = sc[b]; bi = b; }
      if (bi < 0) break;
      m_ |= 1u << bi;
      sc[bi] = -INFINITY;
    }
    sel[t * NG + g] = m_;
  }
}

// ------- MFMA flash attention, transposed, in-wg split-K (2-way):
// 8 waves: waves {w, w+4} same head, interleaved halves of block list;
// bf16 LDS merge. NOTE __launch_bounds__ 2nd arg acts as CUDA min-blocks/CU
// on this compiler: (512,2) -> 16 waves/CU -> 128-VGPR cap (fits ~124, NO
// spill; (512,4) forced 64 VGPR and spilled 1GB to scratch in round 5).
__global__ __launch_bounds__(512, 2) void mfma_attn(
    const ushort* __restrict__ qb16, const ushort* __restrict__ kb16,
    const ushort* __restrict__ vtb, const float* __restrict__ kvg,
    const unsigned* __restrict__ sel, float* __restrict__ comb1,
    float* __restrict__ comb2) {
  const int qb = blockIdx.x, g = blockIdx.y;
  const int hg = blockIdx.z & 3, mode = blockIdx.z >> 2;
  const int tid = threadIdx.x, lane = tid & 63, w = tid >> 6;
  const int quad = lane >> 4, l16 = lane & 15;
  const int head = g * 16 + hg * 4 + (w & 3);
  const int split = w >> 2;
  const int t0 = qb * 64;

  __shared__ unsigned sel_s[64];
  __shared__ float pml[4][2][4][64];      // [w-4][m|l][qt][lane]  8 KB
  __shared__ short4_t pacc[4][4][4][64];  // [w-4][dt][qt][lane] bf16 32 KB

  if (tid < 64) sel_s[tid] = sel[(size_t)(t0 + tid) * NG + g];
  __syncthreads();

  short8_t qB[4][2];
  #pragma unroll
  for (int qt = 0; qt < 4; ++qt)
    #pragma unroll
    for (int kd = 0; kd < 2; ++kd)
      qB[qt][kd] = *(const short8_t*)(qb16 +
          ((size_t)(t0 + qt * 16 + l16) * NHQ + head) * HD + kd * 32 + quad * 8);

  unsigned sbq[4];
  #pragma unroll
  for (int qt = 0; qt < 4; ++qt) sbq[qt] = sel_s[qt * 16 + l16];

  float m_[4], l_[4];
  f32x4 acc[4][4];
  const f32x4 fz = {0.f, 0.f, 0.f, 0.f};
  #pragma unroll
  for (int qt = 0; qt < 4; ++qt) { m_[qt] = -1e30f; l_[qt] = 0.f; }
  #pragma unroll
  for (int dt = 0; dt < 4; ++dt)
    #pragma unroll
    for (int qt = 0; qt < 4; ++qt) acc[dt][qt] = fz;

  // my half of the block list (interleaved for balance)
  unsigned mrem = 0; int b0 = 0, nb = 0;
  if (mode == 0) {
    unsigned uni = 0;
    for (int i = 0; i < 64; ++i) uni |= sel_s[i];
    int cnt = 0;
    while (uni) {
      int b = __ffs(uni) - 1; uni &= uni - 1;
      if ((cnt++ & 1) == split) mrem |= 1u << b;
    }
    nb = __popc(mrem);
  } else {
    b0 = ((qb > 8) ? qb - 8 : 0) + split;
    nb = (qb >= b0) ? (qb - b0) / 2 + 1 : 0;
  }

  for (int ib = 0; ib < nb; ++ib) {
    int blk;
    if (mode == 0) { blk = __ffs(mrem) - 1; mrem &= mrem - 1; } else { blk = b0 + 2 * ib; }

    // S^T = K Q^T
    f32x4 sp[4][4];
    #pragma unroll
    for (int kt = 0; kt < 4; ++kt) {
      const ushort* kr = kb16 + (size_t)(blk * 64 + kt * 16 + l16) * 128 + g * 64 + quad * 8;
      short8_t kA0 = *(const short8_t*)kr;
      short8_t kA1 = *(const short8_t*)(kr + 32);
      #pragma unroll
      for (int qt = 0; qt < 4; ++qt) {
        f32x4 c = __builtin_amdgcn_mfma_f32_16x16x32_bf16(kA0, qB[qt][0], fz, 0, 0, 0);
        sp[kt][qt] = __builtin_amdgcn_mfma_f32_16x16x32_bf16(kA1, qB[qt][1], c, 0, 0, 0);
      }
    }

    // mask (-inf) + online softmax; m_ floor -1e30 makes any block order safe
    short4_t pB[4][4];
    #pragma unroll
    for (int qt = 0; qt < 4; ++qt) {
      const int qg = t0 + qt * 16 + l16;
      float mx = -INFINITY;
      #pragma unroll
      for (int kt = 0; kt < 4; ++kt)
        #pragma unroll
        for (int r = 0; r < 4; ++r) {
          int key = blk * 64 + kt * 16 + quad * 4 + r;
          bool ok = (key <= qg) &&
                    (mode == 0 ? (((sbq[qt] >> blk) & 1u) != 0) : (qg - key <= 512));
          float s_ = ok ? sp[kt][qt][r] * SCALE : -INFINITY;
          sp[kt][qt][r] = s_;
          mx = fmaxf(mx, s_);
        }
      mx = fmaxf(mx, __shfl_xor(mx, 16));
      mx = fmaxf(mx, __shfl_xor(mx, 32));
      float mnew = fmaxf(m_[qt], mx);  // >= -1e30 always
      float alpha = __expf(m_[qt] - mnew);
      m_[qt] = mnew;
      float ps = 0.f;
      #pragma unroll
      for (int kt = 0; kt < 4; ++kt) {
        short4_t pb;
        #pragma unroll
        for (int r = 0; r < 4; ++r) {
          float p = __expf(sp[kt][qt][r] - mnew);  // exp(-inf)=0
          ps += p;
          pb[r] = pbf(p);
        }
        pB[kt][qt] = pb;
      }
      ps += __shfl_xor(ps, 16);
      ps += __shfl_xor(ps, 32);
      l_[qt] = l_[qt] * alpha + ps;
      #pragma unroll
      for (int dt = 0; dt < 4; ++dt)
        #pragma unroll
        for (int r = 0; r < 4; ++r) acc[dt][qt][r] *= alpha;
    }

    // O^T += V^T P^T
    #pragma unroll
    for (int kt = 0; kt < 4; ++kt) {
      short4_t vA[4];
      #pragma unroll
      for (int dt = 0; dt < 4; ++dt)
        vA[dt] = *(const short4_t*)(vtb +
            ((size_t)g * HD + dt * 16 + l16) * T_SEQ + blk * 64 + kt * 16 + quad * 4);
      #pragma unroll
      for (int dt = 0; dt < 4; ++dt)
        #pragma unroll
        for (int qt = 0; qt < 4; ++qt)
          acc[dt][qt] = __builtin_amdgcn_mfma_f32_16x16x16bf16_1k(
              vA[dt], pB[kt][qt], acc[dt][qt], 0, 0, 0);
    }
  }

  // publish split-1 partials, merge in split-0 waves
  if (split == 1) {
    const int w4 = w & 3;
    #pragma unroll
    for (int qt = 0; qt < 4; ++qt) {
      pml[w4][0][qt][lane] = m_[qt];
      pml[w4][1][qt][lane] = l_[qt];
    }
    #pragma unroll
    for (int dt = 0; dt < 4; ++dt)
      #pragma unroll
      for (int qt = 0; qt < 4; ++qt) {
        short4_t pk;
        #pragma unroll
        for (int r = 0; r < 4; ++r) pk[r] = (short)f2bf(acc[dt][qt][r]);
        pacc[w4][dt][qt][lane] = pk;
      }
  }
  __syncthreads();
  if (split == 0) {
    float a1[4], a2[4];
    #pragma unroll
    for (int qt = 0; qt < 4; ++qt) {
      float m2 = pml[w][0][qt][lane], l2 = pml[w][1][qt][lane];
      float mN = fmaxf(m_[qt], m2);
      a1[qt] = __expf(m_[qt] - mN);
      a2[qt] = __expf(m2 - mN);
      l_[qt] = l_[qt] * a1[qt] + l2 * a2[qt];
    }
    #pragma unroll
    for (int dt = 0; dt < 4; ++dt)
      #pragma unroll
      for (int qt = 0; qt < 4; ++qt) {
        short4_t pk = pacc[w][dt][qt][lane];
        #pragma unroll
        for (int r = 0; r < 4; ++r)
          acc[dt][qt][r] = acc[dt][qt][r] * a1[qt] + bf2f((ushort)pk[r]) * a2[qt];
      }
    // epilogue
    #pragma unroll
    for (int qt = 0; qt < 4; ++qt) {
      const int t = t0 + qt * 16 + l16;
      const float c_ =
          (1.f / (1.f + __expf(-kvg[(size_t)t * KVGW + 257 + mode]))) / l_[qt];
      #pragma unroll
      for (int dt = 0; dt < 4; ++dt)
        #pragma unroll
        for (int r = 0; r < 4; ++r) {
          const int d = dt * 16 + quad * 4 + r;
          size_t idx = ((size_t)t * NHQ + head) * HD + d;
          if (mode == 0) comb1[idx] += c_ * acc[dt][qt][r];
          else           comb2[idx]  = c_ * acc[dt][qt][r];
        }
    }
  }
}

extern "C" void kernel_launch(void* const* d_in, const int* in_sizes, int n_in,
                              void* d_out, int out_size, void* d_ws, size_t ws_size,
                              hipStream_t stream) {
  const float* x   = (const float*)d_in[0];
  const float* Wq  = (const float*)d_in[1];
  const float* Wk  = (const float*)d_in[2];
  const float* Wv  = (const float*)d_in[3];
  const float* Wo  = (const float*)d_in[4];
  const float* Wg  = (const float*)d_in[5];
  const float* Wck = (const float*)d_in[6];
  const float* Wcv = (const float*)d_in[7];
  float* out = (float*)d_out;
  float* ws = (float*)d_ws;

  float* qbuf   = ws;                           // 4,194,304 f
  float* comb1  = qbuf + 4194304;               // 4,194,304 f
  float* kvg    = comb1 + 4194304;              //   786,432 f
  float* ckb    = kvg + 786432;                 //    16,384 f
  float* cvb    = ckb + 16384;                  //    16,384 f
  unsigned* sel = (unsigned*)(cvb + 16384);     //     4,096 u32
  ushort* kbf   = (ushort*)(sel + 4096);        //   262,144 u16
  ushort* vtb   = kbf + 262144;                 //   262,144 u16
  ushort* wkvgb = vtb + 262144;                 //   786,432 u16
  ushort* regA  = wkvgb + 786432;               // 4,194,304 u16: xb -> combb
  ushort* regB  = regA + 4194304;               // 4,194,304 u16: wqb -> qbf
  ushort* xb = regA;      ushort* combb = regA;
  ushort* wqb = regB;     ushort* qbf = regB;
  float* comb2 = qbuf;                // fp32 q dead after rope_all
  ushort* wob = (ushort*)qbuf;        // written after comb2 consumed

  const int CV = (4194304 + 255) / 256;
  cvt_bf<<<CV, 256, 0, stream>>>(x, xb, 4194304);
  cvt_bf<<<CV, 256, 0, stream>>>(Wq, wqb, 4194304);
  pack_wkvg<<<(KVGW * 2048 + 255) / 256, 256, 0, stream>>>(Wk, Wv, Wg, wkvgb);

  mgemm<<<dim3(16, 16), 256, 0, stream>>>(xb, wqb, qbuf, 2048, 2048, 2048);
  mgemm<<<dim3(3, 16), 256, 0, stream>>>(xb, wkvgb, kvg, 2048, KVGW, 2048);

  rope_all<<<2048, 256, 0, stream>>>(qbuf, kvg, qbf, kbf);
  cvt_vt<<<(262144 + 255) / 256, 256, 0, stream>>>(kvg, vtb);
  compress_kv<<<dim3(127, 2), 256, 0, stream>>>(kvg, Wck, Wcv, ckb, cvb);
  comp_attn<<<dim3(2048, 2), 128, 0, stream>>>(qbf, ckb, cvb, kvg, comb1, sel);
  mfma_attn<<<dim3(32, 2, 8), 512, 0, stream>>>(qbf, kbf, vtb, kvg, sel, comb1, comb2);

  cvt_sum2_bf<<<CV, 256, 0, stream>>>(comb1, comb2, combb, 4194304);
  cvt_bf<<<CV, 256, 0, stream>>>(Wo, wob, 4194304);
  mgemm<<<dim3(16, 16), 256, 0, stream>>>(combb, wob, out, 2048, 2048, 2048);
}